// Round 1
// baseline (2125.791 us; speedup 1.0000x reference)
//
#include <hip/hip_runtime.h>

#define THREADS 256

// Y = relu( [bias +] X @ W ), W is (K,100) row-major, read via L1/L2 (not staged).
// MODE 0: X[r,k] = p0[r*K + k]                       (plain, K=147, f_bonds)
// MODE 1: X[r,k] = p1[i1[r]*100+k] - p0[i0[r]*100+k] (a_message[b2a] - message[b2revb], K=100)
// MODE 2: X[r,k] = k<133 ? p0[r*133+k] : p1[r*100+k-133]  (concat(f_atoms, a_message), K=233)
template<int K, int MODE, int TM>
__global__ __launch_bounds__(THREADS) void mm_relu(
    const float* __restrict__ p0, const float* __restrict__ p1,
    const int* __restrict__ i0, const int* __restrict__ i1,
    const float* __restrict__ W, const float* __restrict__ bias,
    float* __restrict__ Y, int M)
{
    constexpr int KS = (K % 2 == 0) ? K + 1 : K;   // pad even K to kill bank aliasing
    constexpr int RPT = TM / 8;                    // rows per thread (8 row-groups)
    __shared__ float Xs[TM * KS];
    __shared__ int sA[TM], sB[TM];

    const int tid = threadIdx.x;
    const int row0 = blockIdx.x * TM;

    if (MODE == 1) {
        if (tid < TM) {
            int r = row0 + tid; if (r >= M) r = M - 1;
            sA[tid] = i1[r];   // b2a
            sB[tid] = i0[r];   // b2revb
        }
        __syncthreads();
    }

    // stage X tile into LDS (coalesced along k)
    for (int i = tid; i < TM * K; i += THREADS) {
        int rl = i / K;
        int k  = i - rl * K;
        float v;
        if (MODE == 0) {
            int r = row0 + rl; if (r >= M) r = M - 1;
            v = p0[(size_t)r * K + k];
        } else if (MODE == 1) {
            v = p1[(size_t)sA[rl] * 100 + k] - p0[(size_t)sB[rl] * 100 + k];
        } else {
            int r = row0 + rl; if (r >= M) r = M - 1;
            v = (k < 133) ? p0[(size_t)r * 133 + k] : p1[(size_t)r * 100 + (k - 133)];
        }
        Xs[rl * KS + k] = v;
    }
    __syncthreads();

    const int cg = tid & 31;      // column group: cols cg, cg+32, cg+64, cg+96
    const int rg = tid >> 5;      // row group: rows rg*RPT .. rg*RPT+RPT-1
    const bool has4 = (cg + 96) < 100;

    float acc[RPT][4];
    #pragma unroll
    for (int i = 0; i < RPT; ++i)
        for (int j = 0; j < 4; ++j) acc[i][j] = 0.f;

    for (int k = 0; k < K; ++k) {
        const float* wk = W + k * 100 + cg;
        float w0 = wk[0], w1 = wk[32], w2 = wk[64];
        float w3 = has4 ? wk[96] : 0.f;
        #pragma unroll
        for (int i = 0; i < RPT; ++i) {
            float x = Xs[(rg * RPT + i) * KS + k];
            acc[i][0] = fmaf(x, w0, acc[i][0]);
            acc[i][1] = fmaf(x, w1, acc[i][1]);
            acc[i][2] = fmaf(x, w2, acc[i][2]);
            acc[i][3] = fmaf(x, w3, acc[i][3]);
        }
    }

    #pragma unroll
    for (int i = 0; i < RPT; ++i) {
        int r = row0 + rg * RPT + i;
        if (r < M) {
            float* y = Y + (size_t)r * 100 + cg;
            float b0 = 0.f, b1 = 0.f, b2 = 0.f, b3 = 0.f;
            if (bias) {
                const float* bb = bias + (size_t)r * 100 + cg;
                b0 = bb[0]; b1 = bb[32]; b2 = bb[64];
                if (has4) b3 = bb[96];
            }
            y[0]  = fmaxf(acc[i][0] + b0, 0.f);
            y[32] = fmaxf(acc[i][1] + b1, 0.f);
            y[64] = fmaxf(acc[i][2] + b2, 0.f);
            if (has4) y[96] = fmaxf(acc[i][3] + b3, 0.f);
        }
    }
}

// a_message[a] = sum_{j<6} message[a2b[a][j]]  — row = 25 float4s
__global__ __launch_bounds__(THREADS) void gather_sum(
    const float4* __restrict__ msg, const int* __restrict__ a2b,
    float4* __restrict__ amsg, int A)
{
    int t = blockIdx.x * THREADS + threadIdx.x;
    if (t >= A * 25) return;
    int a = t / 25;
    int c = t - a * 25;
    const int* nb = a2b + (size_t)a * 6;
    float4 s = make_float4(0.f, 0.f, 0.f, 0.f);
    #pragma unroll
    for (int j = 0; j < 6; ++j) {
        float4 v = msg[(size_t)nb[j] * 25 + c];
        s.x += v.x; s.y += v.y; s.z += v.z; s.w += v.w;
    }
    amsg[(size_t)a * 25 + c] = s;
}

// per-molecule mean of atom_hiddens over sorted mol_id segments, concat f_mol
__global__ __launch_bounds__(128) void readout(
    const float* __restrict__ atom_h, const float* __restrict__ f_mol,
    const int* __restrict__ mol_id, int n_atoms, float* __restrict__ out_mol)
{
    int m = blockIdx.x;
    int lo = 0, hi = n_atoms;
    while (lo < hi) { int mid = (lo + hi) >> 1; if (mol_id[mid] < m) lo = mid + 1; else hi = mid; }
    int lo2 = lo, hi2 = n_atoms;
    while (lo2 < hi2) { int mid = (lo2 + hi2) >> 1; if (mol_id[mid] < m + 1) lo2 = mid + 1; else hi2 = mid; }
    int cnt = lo2 - lo;
    float inv = 1.0f / fmaxf((float)cnt, 1.0f);
    int c = threadIdx.x;
    if (c < 100) {
        float s = 0.f;
        for (int a = lo; a < lo2; ++a) s += atom_h[(size_t)a * 100 + c];
        out_mol[(size_t)m * 108 + c] = s * inv;
    } else if (c < 108) {
        out_mol[(size_t)m * 108 + c] = f_mol[(size_t)m * 8 + (c - 100)];
    }
}

extern "C" void kernel_launch(void* const* d_in, const int* in_sizes, int n_in,
                              void* d_out, int out_size, void* d_ws, size_t ws_size,
                              hipStream_t stream)
{
    const float* f_atoms = (const float*)d_in[0];
    const float* f_bonds = (const float*)d_in[1];
    const float* f_mol   = (const float*)d_in[2];
    const float* W_i     = (const float*)d_in[3];
    const float* W_h     = (const float*)d_in[4];
    const float* W_o     = (const float*)d_in[5];
    const int* a2b    = (const int*)d_in[6];
    const int* b2a    = (const int*)d_in[7];
    const int* b2revb = (const int*)d_in[8];
    const int* mol_id = (const int*)d_in[9];

    const int A    = in_sizes[0] / 133;   // n_atoms
    const int B    = in_sizes[1] / 147;   // n_bonds
    const int Mmol = in_sizes[2] / 8;     // n_mols

    float* ws   = (float*)d_ws;
    float* inp  = ws;                           // (B,100)
    float* msgA = ws   + (size_t)B * 100;       // (B,100)
    float* msgB = msgA + (size_t)B * 100;       // (B,100)
    float* amsg = msgB + (size_t)B * 100;       // (A,100)

    float* out     = (float*)d_out;
    float* out_mol = out;                       // (Mmol,108)
    float* atom_h  = out + (size_t)Mmol * 108;  // (A,100)

    dim3 blk(THREADS);
    int gb64 = (B + 63) / 64;
    int ga32 = (A + 31) / 32;
    int gg   = (A * 25 + THREADS - 1) / THREADS;

    // inp = relu(f_bonds @ W_i)
    mm_relu<147, 0, 64><<<gb64, blk, 0, stream>>>(f_bonds, nullptr, nullptr, nullptr, W_i, nullptr, inp, B);

    // depth iteration 1 (message == inp)
    gather_sum<<<gg, blk, 0, stream>>>((const float4*)inp, a2b, (float4*)amsg, A);
    mm_relu<100, 1, 64><<<gb64, blk, 0, stream>>>(inp, amsg, b2revb, b2a, W_h, inp, msgA, B);

    // depth iteration 2
    gather_sum<<<gg, blk, 0, stream>>>((const float4*)msgA, a2b, (float4*)amsg, A);
    mm_relu<100, 1, 64><<<gb64, blk, 0, stream>>>(msgA, amsg, b2revb, b2a, W_h, inp, msgB, B);

    // final neighbor aggregation
    gather_sum<<<gg, blk, 0, stream>>>((const float4*)msgB, a2b, (float4*)amsg, A);

    // atom_hiddens = relu(concat(f_atoms, a_msg) @ W_o)  -> directly into d_out
    mm_relu<233, 2, 32><<<ga32, blk, 0, stream>>>(f_atoms, amsg, nullptr, nullptr, W_o, nullptr, atom_h, A);

    // per-molecule mean + concat f_mol
    readout<<<Mmol, dim3(128), 0, stream>>>(atom_h, f_mol, mol_id, A, out_mol);
}

// Round 2
// 1393.649 us; speedup vs baseline: 1.5253x; 1.5253x over previous
//
#include <hip/hip_runtime.h>

#define THREADS 256

typedef __bf16 bf16x8 __attribute__((ext_vector_type(8)));
typedef float f32x4 __attribute__((ext_vector_type(4)));

__device__ __forceinline__ unsigned short f2b(float x) {
    unsigned int u = __float_as_uint(x);
    u = (u + 0x7FFFu + ((u >> 16) & 1u)) >> 16;
    return (unsigned short)u;
}
__device__ __forceinline__ float b2f(unsigned short h) {
    return __uint_as_float(((unsigned int)h) << 16);
}

// Pack W (K,100) fp32 row-major -> B-fragment-ordered bf16, padded to KH x 112.
// frag element: lane l, reg j -> B[k = kc*32 + (l>>4)*8 + j][n = nt*16 + (l&15)]
// stored at out[((kc*7+nt)*64 + l)*8 + j]. grid = (KH/32)*7 blocks of 64.
__global__ __launch_bounds__(64) void pack_w(const float* __restrict__ W,
                                             unsigned short* __restrict__ out, int K)
{
    int bid = blockIdx.x;
    int kc = bid / 7, nt = bid - kc * 7;
    int l = threadIdx.x;
    int k0 = kc * 32 + (l >> 4) * 8;
    int n = nt * 16 + (l & 15);
    unsigned short v[8];
    #pragma unroll
    for (int j = 0; j < 8; ++j) {
        int k = k0 + j;
        float x = (k < K && n < 100) ? W[(size_t)k * 100 + n] : 0.f;
        v[j] = f2b(x);
    }
    *(uint4*)&out[((size_t)bid * 64 + l) * 8] = *(uint4*)v;
}

// a_message[a] = sum_{j<6} message[a2b[a][j]]  (bf16 rows, 112-col zero-padded stride)
__global__ __launch_bounds__(THREADS) void gather_sum_bf16(
    const unsigned short* __restrict__ msg, const int* __restrict__ a2b,
    unsigned short* __restrict__ amsg, int A)
{
    int t = blockIdx.x * THREADS + threadIdx.x;
    if (t >= A * 14) return;
    int a = t / 14;
    int c = t - a * 14;
    const int* nb = a2b + (size_t)a * 6;
    float s[8];
    #pragma unroll
    for (int e = 0; e < 8; ++e) s[e] = 0.f;
    #pragma unroll
    for (int j = 0; j < 6; ++j) {
        uint4 v = *(const uint4*)&msg[(size_t)nb[j] * 112 + c * 8];
        const unsigned short* pv = (const unsigned short*)&v;
        #pragma unroll
        for (int e = 0; e < 8; ++e) s[e] += b2f(pv[e]);
    }
    unsigned short r[8];
    #pragma unroll
    for (int e = 0; e < 8; ++e) r[e] = f2b(s[e]);
    *(uint4*)&amsg[(size_t)a * 112 + c * 8] = *(uint4*)r;
}

// Y = relu([bias +] X @ W) via bf16 MFMA 16x16x32. N padded to 112, K padded to KH.
// MODE 0: X from f_bonds fp32 (K=147). out bf16 (B,112)
// MODE 1: X[r] = amsg[i0[r]] - msg[i1[r]] (bf16), bias=inp. out bf16 (B,112)
// MODE 2: X[r] = concat(f_atoms fp32 133, amsg bf16 100). out fp32 (A,100)
// TM rows/block (RT=TM/64 row-tiles of 16 per wave), 256 threads = 4 waves.
template<int K, int KH, int MODE, int TM>
__global__ __launch_bounds__(THREADS) void mfma_mm(
    const float* __restrict__ fA, const unsigned short* __restrict__ gA,
    const unsigned short* __restrict__ gB,
    const int* __restrict__ i0, const int* __restrict__ i1,
    const unsigned short* __restrict__ wf, const unsigned short* __restrict__ bias,
    unsigned short* __restrict__ Yb, float* __restrict__ Yf, int M)
{
    constexpr int RT  = TM / 64;     // row-tiles of 16 per wave
    constexpr int KS  = KH + 8;      // LDS row stride (bf16 elems), breaks bank alias
    constexpr int NKC = KH / 32;
    __shared__ unsigned short Xs[TM * KS];
    __shared__ int sA[(MODE == 1) ? TM : 1];
    __shared__ int sB[(MODE == 1) ? TM : 1];

    const int tid = threadIdx.x;
    const int row0 = blockIdx.x * TM;

    if (MODE == 1) {
        if (tid < TM) {
            int r = row0 + tid; if (r >= M) r = M - 1;
            sA[tid] = i0[r];
            sB[tid] = i1[r];
        }
        __syncthreads();
    }

    // ---- stage X tile into LDS as bf16 ----
    if (MODE == 1) {
        constexpr int CH = KS / 8;   // 16B chunks per row (17 for KH=128)
        for (int i = tid; i < TM * CH; i += THREADS) {
            int rl = i / CH;
            int c  = i - rl * CH;
            uint4 o;
            if (c < 14) {   // 14 chunks = 112 real cols
                uint4 va = *(const uint4*)&gA[(size_t)sA[rl] * 112 + c * 8];
                uint4 vb = *(const uint4*)&gB[(size_t)sB[rl] * 112 + c * 8];
                const unsigned short* ua = (const unsigned short*)&va;
                const unsigned short* ub = (const unsigned short*)&vb;
                unsigned short res[8];
                #pragma unroll
                for (int e = 0; e < 8; ++e) res[e] = f2b(b2f(ua[e]) - b2f(ub[e]));
                o = *(uint4*)res;
            } else {
                o = make_uint4(0u, 0u, 0u, 0u);
            }
            *(uint4*)&Xs[(size_t)rl * KS + c * 8] = o;
        }
    } else if (MODE == 0) {
        for (int i = tid; i < TM * KS; i += THREADS) {
            int rl = i / KS;
            int k  = i - rl * KS;
            int r = row0 + rl; if (r >= M) r = M - 1;
            Xs[i] = (k < K) ? f2b(fA[(size_t)r * K + k]) : (unsigned short)0;
        }
    } else {
        for (int i = tid; i < TM * KS; i += THREADS) {
            int rl = i / KS;
            int k  = i - rl * KS;
            int r = row0 + rl; if (r >= M) r = M - 1;
            unsigned short v;
            if (k < 133)       v = f2b(fA[(size_t)r * 133 + k]);
            else if (k < 233)  v = gA[(size_t)r * 112 + (k - 133)];
            else               v = 0;
            Xs[i] = v;
        }
    }
    __syncthreads();

    // ---- MFMA compute: each wave: RT row-tiles x 7 n-tiles ----
    const int l = tid & 63, w = tid >> 6;
    const int quad = l >> 4, c15 = l & 15;

    f32x4 acc[RT][7];
    #pragma unroll
    for (int rt = 0; rt < RT; ++rt)
        #pragma unroll
        for (int nt = 0; nt < 7; ++nt)
            acc[rt][nt] = (f32x4){0.f, 0.f, 0.f, 0.f};

    for (int kc = 0; kc < NKC; ++kc) {
        bf16x8 av[RT];
        #pragma unroll
        for (int rt = 0; rt < RT; ++rt)
            av[rt] = *(const bf16x8*)&Xs[(size_t)(w * (RT * 16) + rt * 16 + c15) * KS + kc * 32 + quad * 8];
        #pragma unroll
        for (int nt = 0; nt < 7; ++nt) {
            bf16x8 bv = *(const bf16x8*)&wf[((size_t)(kc * 7 + nt) * 64 + l) * 8];
            #pragma unroll
            for (int rt = 0; rt < RT; ++rt)
                acc[rt][nt] = __builtin_amdgcn_mfma_f32_16x16x32_bf16(av[rt], bv, acc[rt][nt], 0, 0, 0);
        }
    }

    // ---- epilogue: bias + relu + store ----
    #pragma unroll
    for (int rt = 0; rt < RT; ++rt) {
        #pragma unroll
        for (int reg = 0; reg < 4; ++reg) {
            int r = row0 + w * (RT * 16) + rt * 16 + quad * 4 + reg;
            if (r < M) {
                #pragma unroll
                for (int nt = 0; nt < 7; ++nt) {
                    int n = nt * 16 + c15;
                    float v = acc[rt][nt][reg];
                    if (MODE == 1) v += b2f(bias[(size_t)r * 112 + n]);
                    v = fmaxf(v, 0.f);
                    if (MODE == 2) {
                        if (n < 100) Yf[(size_t)r * 100 + n] = v;
                    } else {
                        Yb[(size_t)r * 112 + n] = f2b(v);
                    }
                }
            }
        }
    }
}

// per-molecule mean of atom_hiddens (fp32, stride 100) over sorted mol_id, concat f_mol
__global__ __launch_bounds__(128) void readout(
    const float* __restrict__ atom_h, const float* __restrict__ f_mol,
    const int* __restrict__ mol_id, int n_atoms, float* __restrict__ out_mol)
{
    int m = blockIdx.x;
    int lo = 0, hi = n_atoms;
    while (lo < hi) { int mid = (lo + hi) >> 1; if (mol_id[mid] < m) lo = mid + 1; else hi = mid; }
    int lo2 = lo, hi2 = n_atoms;
    while (lo2 < hi2) { int mid = (lo2 + hi2) >> 1; if (mol_id[mid] < m + 1) lo2 = mid + 1; else hi2 = mid; }
    float inv = 1.0f / fmaxf((float)(lo2 - lo), 1.0f);
    int c = threadIdx.x;
    if (c < 100) {
        float s = 0.f;
        for (int a = lo; a < lo2; ++a) s += atom_h[(size_t)a * 100 + c];
        out_mol[(size_t)m * 108 + c] = s * inv;
    } else if (c < 108) {
        out_mol[(size_t)m * 108 + c] = f_mol[(size_t)m * 8 + (c - 100)];
    }
}

extern "C" void kernel_launch(void* const* d_in, const int* in_sizes, int n_in,
                              void* d_out, int out_size, void* d_ws, size_t ws_size,
                              hipStream_t stream)
{
    const float* f_atoms = (const float*)d_in[0];
    const float* f_bonds = (const float*)d_in[1];
    const float* f_mol   = (const float*)d_in[2];
    const float* W_i     = (const float*)d_in[3];
    const float* W_h     = (const float*)d_in[4];
    const float* W_o     = (const float*)d_in[5];
    const int* a2b    = (const int*)d_in[6];
    const int* b2a    = (const int*)d_in[7];
    const int* b2revb = (const int*)d_in[8];
    const int* mol_id = (const int*)d_in[9];

    const int A    = in_sizes[0] / 133;
    const int B    = in_sizes[1] / 147;
    const int Mmol = in_sizes[2] / 8;

    unsigned short* wsu = (unsigned short*)d_ws;
    unsigned short* wfi  = wsu;                            // 5*7*512 = 17920
    unsigned short* wfh  = wfi + 35 * 512;                 // 4*7*512 = 14336
    unsigned short* wfo  = wfh + 28 * 512;                 // 8*7*512 = 28672
    unsigned short* inp  = wfo + 56 * 512;                 // (B,112) bf16
    unsigned short* msgA = inp  + (size_t)B * 112;
    unsigned short* msgB = msgA + (size_t)B * 112;
    unsigned short* amsg = msgB + (size_t)B * 112;         // (A,112) bf16

    float* out     = (float*)d_out;
    float* out_mol = out;
    float* atom_h  = out + (size_t)Mmol * 108;

    dim3 blk(THREADS);
    int gmB = (B + 127) / 128;
    int gmA = (A + 63) / 64;
    int gg  = (A * 14 + THREADS - 1) / THREADS;

    pack_w<<<35, dim3(64), 0, stream>>>(W_i, wfi, 147);
    pack_w<<<28, dim3(64), 0, stream>>>(W_h, wfh, 100);
    pack_w<<<56, dim3(64), 0, stream>>>(W_o, wfo, 233);

    // inp = relu(f_bonds @ W_i)
    mfma_mm<147, 160, 0, 128><<<gmB, blk, 0, stream>>>(
        f_bonds, nullptr, nullptr, nullptr, nullptr, wfi, nullptr, inp, nullptr, B);

    // depth 1
    gather_sum_bf16<<<gg, blk, 0, stream>>>(inp, a2b, amsg, A);
    mfma_mm<100, 128, 1, 128><<<gmB, blk, 0, stream>>>(
        nullptr, amsg, inp, b2a, b2revb, wfh, inp, msgA, nullptr, B);

    // depth 2
    gather_sum_bf16<<<gg, blk, 0, stream>>>(msgA, a2b, amsg, A);
    mfma_mm<100, 128, 1, 128><<<gmB, blk, 0, stream>>>(
        nullptr, amsg, msgA, b2a, b2revb, wfh, inp, msgB, nullptr, B);

    // final aggregation + readout GEMM
    gather_sum_bf16<<<gg, blk, 0, stream>>>(msgB, a2b, amsg, A);
    mfma_mm<233, 256, 2, 64><<<gmA, blk, 0, stream>>>(
        f_atoms, amsg, nullptr, nullptr, nullptr, wfo, nullptr, nullptr, atom_h, A);

    readout<<<Mmol, dim3(128), 0, stream>>>(atom_h, f_mol, mol_id, A, out_mol);
}

// Round 3
// 1096.414 us; speedup vs baseline: 1.9389x; 1.2711x over previous
//
#include <hip/hip_runtime.h>

#define THREADS 256

typedef __bf16 bf16x8 __attribute__((ext_vector_type(8)));
typedef float f32x4 __attribute__((ext_vector_type(4)));
typedef float f32x4u __attribute__((ext_vector_type(4), aligned(4)));

__device__ __forceinline__ unsigned short f2b(float x) {
    unsigned int u = __float_as_uint(x);
    u = (u + 0x7FFFu + ((u >> 16) & 1u)) >> 16;
    return (unsigned short)u;
}
__device__ __forceinline__ float b2f(unsigned short h) {
    return __uint_as_float(((unsigned int)h) << 16);
}
__device__ __forceinline__ bf16x8 as_bf(uint4 q) {
    union { uint4 q; bf16x8 v; } u; u.q = q; return u.v;
}

// ---- W pack: (K,100) fp32 row-major -> B-frag bf16, KH x 112 padded ----
// lane l, reg j -> B[k = kc*32 + (l>>4)*8 + j][n = nt*16 + (l&15)]
__global__ __launch_bounds__(64) void pack_w(const float* __restrict__ W,
                                             unsigned short* __restrict__ out, int K)
{
    int bid = blockIdx.x;
    int kc = bid / 7, nt = bid - kc * 7;
    int l = threadIdx.x;
    int k0 = kc * 32 + (l >> 4) * 8;
    int n = nt * 16 + (l & 15);
    unsigned short v[8];
    #pragma unroll
    for (int j = 0; j < 8; ++j) {
        int k = k0 + j;
        float x = (k < K && n < 100) ? W[(size_t)k * 100 + n] : 0.f;
        v[j] = f2b(x);
    }
    *(uint4*)&out[((size_t)bid * 64 + l) * 8] = *(uint4*)v;
}

// W_o packed with permuted k: k<100 -> W_o row 133+k (amsg part), 100..111 zero,
// 112..244 -> W_o row k-112 (f_atoms part), >=245 zero. KH=256 -> 56 blocks.
__global__ __launch_bounds__(64) void pack_wo(const float* __restrict__ W,
                                              unsigned short* __restrict__ out)
{
    int bid = blockIdx.x;
    int kc = bid / 7, nt = bid - kc * 7;
    int l = threadIdx.x;
    int k0 = kc * 32 + (l >> 4) * 8;
    int n = nt * 16 + (l & 15);
    unsigned short v[8];
    #pragma unroll
    for (int j = 0; j < 8; ++j) {
        int k = k0 + j;
        float x = 0.f;
        if (n < 100) {
            if (k < 100)                 x = W[(size_t)(133 + k) * 100 + n];
            else if (k >= 112 && k < 245) x = W[(size_t)(k - 112) * 100 + n];
        }
        v[j] = f2b(x);
    }
    *(uint4*)&out[((size_t)bid * 64 + l) * 8] = *(uint4*)v;
}

// ---- a_message[a] = sum_j message[a2b[a][j]] (bf16, stride 112) ----
__global__ __launch_bounds__(THREADS) void gather_sum_bf16(
    const unsigned short* __restrict__ msg, const int* __restrict__ a2b,
    unsigned short* __restrict__ amsg, int A)
{
    int t = blockIdx.x * THREADS + threadIdx.x;
    if (t >= A * 14) return;
    int a = t / 14;
    int c = t - a * 14;
    const int* nb = a2b + (size_t)a * 6;
    float s[8];
    #pragma unroll
    for (int e = 0; e < 8; ++e) s[e] = 0.f;
    #pragma unroll
    for (int j = 0; j < 6; ++j) {
        uint4 v = *(const uint4*)&msg[(size_t)nb[j] * 112 + c * 8];
        const unsigned short* pv = (const unsigned short*)&v;
        #pragma unroll
        for (int e = 0; e < 8; ++e) s[e] += b2f(pv[e]);
    }
    unsigned short r[8];
    #pragma unroll
    for (int e = 0; e < 8; ++e) r[e] = f2b(s[e]);
    *(uint4*)&amsg[(size_t)a * 112 + c * 8] = *(uint4*)r;
}

// ---- inp = relu(f_bonds @ W_i): direct-reg A-frags, no staging LDS ----
__global__ __launch_bounds__(THREADS) void gemm_in(
    const float* __restrict__ fb, const unsigned short* __restrict__ wf,
    unsigned short* __restrict__ Y, int M)
{
    __shared__ unsigned short Os[64 * 136];   // epilogue restage, stride 136
    const int tid = threadIdx.x;
    const int l = tid & 63, w = tid >> 6;
    const int quad = l >> 4, c15 = l & 15;
    const int row0 = blockIdx.x * 64;
    const int rc = min(row0 + w * 16 + c15, M - 1);
    const float* rowp = fb + (size_t)rc * 147;

    uint4 af[5];
    #pragma unroll
    for (int kc = 0; kc < 4; ++kc) {
        f32x4u x0 = *(const f32x4u*)(rowp + kc * 32 + quad * 8);
        f32x4u x1 = *(const f32x4u*)(rowp + kc * 32 + quad * 8 + 4);
        unsigned short t[8];
        #pragma unroll
        for (int e = 0; e < 4; ++e) { t[e] = f2b(x0[e]); t[4 + e] = f2b(x1[e]); }
        af[kc] = *(uint4*)t;
    }
    {   // kc=4: cols 128+quad*8+j, guard k<147
        unsigned short t[8];
        #pragma unroll
        for (int j = 0; j < 8; ++j) {
            int k = 128 + quad * 8 + j;
            t[j] = (k < 147) ? f2b(rowp[k]) : (unsigned short)0;
        }
        af[4] = *(uint4*)t;
    }

    f32x4 acc[7];
    #pragma unroll
    for (int nt = 0; nt < 7; ++nt) acc[nt] = (f32x4){0.f, 0.f, 0.f, 0.f};
    #pragma unroll
    for (int kc = 0; kc < 5; ++kc) {
        #pragma unroll
        for (int nt = 0; nt < 7; ++nt) {
            uint4 bq = *(const uint4*)&wf[((size_t)(kc * 7 + nt) * 64 + l) * 8];
            acc[nt] = __builtin_amdgcn_mfma_f32_16x16x32_bf16(as_bf(af[kc]), as_bf(bq), acc[nt], 0, 0, 0);
        }
    }

    #pragma unroll
    for (int nt = 0; nt < 7; ++nt)
        #pragma unroll
        for (int reg = 0; reg < 4; ++reg)
            Os[(w * 16 + quad * 4 + reg) * 136 + nt * 16 + c15] = f2b(fmaxf(acc[nt][reg], 0.f));
    __syncthreads();

    for (int t = tid; t < 64 * 14; t += THREADS) {
        int rl = t / 14, c = t - rl * 14;
        int rr = row0 + rl;
        if (rr < M)
            *(uint4*)&Y[(size_t)rr * 112 + c * 8] = *(const uint4*)&Os[rl * 136 + c * 8];
    }
}

// ---- message = relu(inp + amsg[b2a]@W - msg[b2revb]@W), dual-MFMA linearity ----
__global__ __launch_bounds__(THREADS) void gemm_msg(
    const unsigned short* __restrict__ amsg, const unsigned short* __restrict__ msg,
    const int* __restrict__ b2a, const int* __restrict__ b2revb,
    const unsigned short* __restrict__ wf, const unsigned short* __restrict__ bias,
    unsigned short* __restrict__ Y, int M)
{
    __shared__ unsigned short Os[64 * 136];
    const int tid = threadIdx.x;
    const int l = tid & 63, w = tid >> 6;
    const int quad = l >> 4, c15 = l & 15;
    const int row0 = blockIdx.x * 64;
    const int rc = min(row0 + w * 16 + c15, M - 1);
    const int iA = b2a[rc], iB = b2revb[rc];
    const unsigned short* pa = amsg + (size_t)iA * 112 + quad * 8;
    const unsigned short* pb = msg  + (size_t)iB * 112 + quad * 8;

    uint4 a1[4], a2[4];
    #pragma unroll
    for (int kc = 0; kc < 4; ++kc) {
        a1[kc] = *(const uint4*)(pa + kc * 32);   // kc=3,quad>=2 overreads next row; W=0 there
        a2[kc] = *(const uint4*)(pb + kc * 32);
    }

    f32x4 acc1[7], acc2[7];
    #pragma unroll
    for (int nt = 0; nt < 7; ++nt) {
        acc1[nt] = (f32x4){0.f, 0.f, 0.f, 0.f};
        acc2[nt] = (f32x4){0.f, 0.f, 0.f, 0.f};
    }
    #pragma unroll
    for (int kc = 0; kc < 4; ++kc) {
        #pragma unroll
        for (int nt = 0; nt < 7; ++nt) {
            uint4 bq = *(const uint4*)&wf[((size_t)(kc * 7 + nt) * 64 + l) * 8];
            acc1[nt] = __builtin_amdgcn_mfma_f32_16x16x32_bf16(as_bf(a1[kc]), as_bf(bq), acc1[nt], 0, 0, 0);
            acc2[nt] = __builtin_amdgcn_mfma_f32_16x16x32_bf16(as_bf(a2[kc]), as_bf(bq), acc2[nt], 0, 0, 0);
        }
    }

    #pragma unroll
    for (int nt = 0; nt < 7; ++nt)
        #pragma unroll
        for (int reg = 0; reg < 4; ++reg)
            Os[(w * 16 + quad * 4 + reg) * 136 + nt * 16 + c15] = f2b(acc1[nt][reg] - acc2[nt][reg]);
    __syncthreads();

    for (int t = tid; t < 64 * 14; t += THREADS) {
        int rl = t / 14, c = t - rl * 14;
        int rr = row0 + rl;
        if (rr < M) {
            uint4 o = *(const uint4*)&Os[rl * 136 + c * 8];
            uint4 bq = *(const uint4*)&bias[(size_t)rr * 112 + c * 8];
            const unsigned short* po = (const unsigned short*)&o;
            const unsigned short* pq = (const unsigned short*)&bq;
            unsigned short res[8];
            #pragma unroll
            for (int e = 0; e < 8; ++e)
                res[e] = f2b(fmaxf(b2f(po[e]) + b2f(pq[e]), 0.f));
            *(uint4*)&Y[(size_t)rr * 112 + c * 8] = *(uint4*)res;
        }
    }
}

// ---- atom_h = relu(concat(amsg, f_atoms)_permuted @ W_o_permuted) ----
__global__ __launch_bounds__(THREADS) void gemm_out(
    const float* __restrict__ fa, const unsigned short* __restrict__ amsg,
    const unsigned short* __restrict__ wf, float* __restrict__ Y, int M)
{
    constexpr int KS = 264;                       // k-stride (KH=256 + 8 pad)
    __shared__ char smem[64 * KS * 2];            // Xs (bf16) then reused as Os (fp32, stride 108)
    unsigned short* Xs = (unsigned short*)smem;
    float* Os = (float*)smem;

    const int tid = threadIdx.x;
    const int l = tid & 63, w = tid >> 6;
    const int quad = l >> 4, c15 = l & 15;
    const int row0 = blockIdx.x * 64;

    for (int t = tid; t < 64 * 33; t += THREADS) {
        int rl = t / 33, c = t - rl * 33;
        int rr = min(row0 + rl, M - 1);
        uint4 o;
        if (c < 14) {                              // amsg -> k 0..111
            o = *(const uint4*)&amsg[(size_t)rr * 112 + c * 8];
        } else if (c < 30) {                       // f_atoms cols (c-14)*8..+7 -> k 112..239
            int cc = c - 14;
            f32x4u x0 = *(const f32x4u*)(fa + (size_t)rr * 133 + cc * 8);
            f32x4u x1 = *(const f32x4u*)(fa + (size_t)rr * 133 + cc * 8 + 4);
            unsigned short tt[8];
            #pragma unroll
            for (int e = 0; e < 4; ++e) { tt[e] = f2b(x0[e]); tt[4 + e] = f2b(x1[e]); }
            o = *(uint4*)tt;
        } else if (c == 30) {                      // f_atoms cols 128..132 -> k 240..247
            unsigned short tt[8];
            #pragma unroll
            for (int j = 0; j < 8; ++j) {
                int col = 128 + j;
                tt[j] = (col < 133) ? f2b(fa[(size_t)rr * 133 + col]) : (unsigned short)0;
            }
            o = *(uint4*)tt;
        } else {
            o = make_uint4(0u, 0u, 0u, 0u);        // k 248..263
        }
        *(uint4*)&Xs[(size_t)rl * KS + c * 8] = o;
    }
    __syncthreads();

    f32x4 acc[7];
    #pragma unroll
    for (int nt = 0; nt < 7; ++nt) acc[nt] = (f32x4){0.f, 0.f, 0.f, 0.f};
    const unsigned short* xrow = Xs + (size_t)(w * 16 + c15) * KS + quad * 8;
    #pragma unroll
    for (int kc = 0; kc < 8; ++kc) {
        bf16x8 av = *(const bf16x8*)(xrow + kc * 32);
        #pragma unroll
        for (int nt = 0; nt < 7; ++nt) {
            uint4 bq = *(const uint4*)&wf[((size_t)(kc * 7 + nt) * 64 + l) * 8];
            acc[nt] = __builtin_amdgcn_mfma_f32_16x16x32_bf16(av, as_bf(bq), acc[nt], 0, 0, 0);
        }
    }
    __syncthreads();   // done reading Xs; reuse as Os

    #pragma unroll
    for (int nt = 0; nt < 7; ++nt) {
        int n = nt * 16 + c15;
        if (n < 100) {
            #pragma unroll
            for (int reg = 0; reg < 4; ++reg)
                Os[(w * 16 + quad * 4 + reg) * 108 + n] = fmaxf(acc[nt][reg], 0.f);
        }
    }
    __syncthreads();

    for (int t = tid; t < 64 * 25; t += THREADS) {
        int rl = t / 25, c = t - rl * 25;
        int rr = row0 + rl;
        if (rr < M)
            *(f32x4*)&Y[(size_t)rr * 100 + c * 4] = *(const f32x4*)&Os[rl * 108 + c * 4];
    }
}

// ---- per-molecule mean + concat f_mol ----
__global__ __launch_bounds__(128) void readout(
    const float* __restrict__ atom_h, const float* __restrict__ f_mol,
    const int* __restrict__ mol_id, int n_atoms, float* __restrict__ out_mol)
{
    int m = blockIdx.x;
    int lo = 0, hi = n_atoms;
    while (lo < hi) { int mid = (lo + hi) >> 1; if (mol_id[mid] < m) lo = mid + 1; else hi = mid; }
    int lo2 = lo, hi2 = n_atoms;
    while (lo2 < hi2) { int mid = (lo2 + hi2) >> 1; if (mol_id[mid] < m + 1) lo2 = mid + 1; else hi2 = mid; }
    float inv = 1.0f / fmaxf((float)(lo2 - lo), 1.0f);
    int c = threadIdx.x;
    if (c < 100) {
        float s = 0.f;
        for (int a = lo; a < lo2; ++a) s += atom_h[(size_t)a * 100 + c];
        out_mol[(size_t)m * 108 + c] = s * inv;
    } else if (c < 108) {
        out_mol[(size_t)m * 108 + c] = f_mol[(size_t)m * 8 + (c - 100)];
    }
}

extern "C" void kernel_launch(void* const* d_in, const int* in_sizes, int n_in,
                              void* d_out, int out_size, void* d_ws, size_t ws_size,
                              hipStream_t stream)
{
    const float* f_atoms = (const float*)d_in[0];
    const float* f_bonds = (const float*)d_in[1];
    const float* f_mol   = (const float*)d_in[2];
    const float* W_i     = (const float*)d_in[3];
    const float* W_h     = (const float*)d_in[4];
    const float* W_o     = (const float*)d_in[5];
    const int* a2b    = (const int*)d_in[6];
    const int* b2a    = (const int*)d_in[7];
    const int* b2revb = (const int*)d_in[8];
    const int* mol_id = (const int*)d_in[9];

    const int A    = in_sizes[0] / 133;
    const int B    = in_sizes[1] / 147;
    const int Mmol = in_sizes[2] / 8;

    unsigned short* wsu = (unsigned short*)d_ws;
    unsigned short* wfi  = wsu;                     // 35*512
    unsigned short* wfh  = wfi + 35 * 512;          // 28*512
    unsigned short* wfo  = wfh + 28 * 512;          // 56*512
    unsigned short* amsg = wfo + 56 * 512;          // (A,112) — overread spills into inp: safe
    unsigned short* inp  = amsg + (size_t)A * 112;  // (B,112)
    unsigned short* msgA = inp  + (size_t)B * 112;
    unsigned short* msgB = msgA + (size_t)B * 112;

    float* out     = (float*)d_out;
    float* out_mol = out;
    float* atom_h  = out + (size_t)Mmol * 108;

    dim3 blk(THREADS);
    int gB = (B + 63) / 64;
    int gA = (A + 63) / 64;
    int gg = (A * 14 + THREADS - 1) / THREADS;

    pack_w<<<35, dim3(64), 0, stream>>>(W_i, wfi, 147);   // KH=160
    pack_w<<<28, dim3(64), 0, stream>>>(W_h, wfh, 100);   // KH=128
    pack_wo<<<56, dim3(64), 0, stream>>>(W_o, wfo);       // KH=256, permuted

    gemm_in<<<gB, blk, 0, stream>>>(f_bonds, wfi, inp, B);

    gather_sum_bf16<<<gg, blk, 0, stream>>>(inp, a2b, amsg, A);
    gemm_msg<<<gB, blk, 0, stream>>>(amsg, inp, b2a, b2revb, wfh, inp, msgA, B);

    gather_sum_bf16<<<gg, blk, 0, stream>>>(msgA, a2b, amsg, A);
    gemm_msg<<<gB, blk, 0, stream>>>(amsg, msgA, b2a, b2revb, wfh, inp, msgB, B);

    gather_sum_bf16<<<gg, blk, 0, stream>>>(msgB, a2b, amsg, A);
    gemm_out<<<gA, blk, 0, stream>>>(f_atoms, amsg, wfo, atom_h, A);

    readout<<<Mmol, dim3(128), 0, stream>>>(atom_h, f_mol, mol_id, A, out_mol);
}